// Round 2
// baseline (63.190 us; speedup 1.0000x reference)
//
#include <hip/hip_runtime.h>
#include <hip/hip_bf16.h>

#define KDIM  1024
#define NOUT  1024
#define MTILE 32
#define BK    32
#define YPAD  1028   // 1024 + 4-float pad: token t shifts banks by 4t

typedef __attribute__((ext_vector_type(8))) short short8;
typedef __attribute__((ext_vector_type(4))) float f32x4;

__device__ static inline unsigned short f2bf(float f) {
    unsigned int u = __float_as_uint(f);
    return (unsigned short)((u + 0x7FFFu + ((u >> 16) & 1u)) >> 16);
}

__device__ static inline void async_copy16(const void* g, void* l) {
    __builtin_amdgcn_global_load_lds(
        (const __attribute__((address_space(1))) void*)g,
        (__attribute__((address_space(3))) void*)l, 16, 0, 0);
}

// ---- weight fp32 [16][1024][64] -> bf16 Bt [n=1024][k=1024], n = h*64+o ----
__global__ __launch_bounds__(256) void conv_w_kernel(const float* __restrict__ W,
                                                     unsigned short* __restrict__ Bt) {
    int u = blockIdx.x * 256 + threadIdx.x;
    int n  = u & (NOUT - 1);
    int k0 = (u >> 10) << 3;
    int h = n >> 6, o = n & 63;
    const float* src = W + (size_t)h * KDIM * 64 + o;
    short8 v;
#pragma unroll
    for (int j = 0; j < 8; ++j)
        v[j] = (short)f2bf(src[(size_t)(k0 + j) * 64]);
    *(short8*)(Bt + (size_t)n * KDIM + k0) = v;
}

// stage full B k-slab [1024 rows][32 k] into LDS; source address carries the
// inverse chunk-swizzle so the linear global_load_lds dest yields swizzled LDS.
__device__ static inline void stage_b(const unsigned short* __restrict__ Bt,
                                      unsigned short* Bl, int tid, int kt) {
#pragma unroll
    for (int i = 0; i < 8; ++i) {
        int slot  = i * 512 + tid;          // 16B slot; lane-contiguous per wave
        int row   = slot >> 2;              // 4 slots (64B) per row
        int kksrc = (((slot & 3) ^ ((row >> 1) & 3)) << 3);
        async_copy16(Bt + (size_t)row * KDIM + kt + kksrc, Bl + (size_t)slot * 8);
    }
}

// ---- fused: x(fp32) -> bf16 A-tile -> GEMM(all N) -> outer+mean+rms -> out ----
__global__ __launch_bounds__(512) void fused_kernel(const float* __restrict__ x,
                                                    const unsigned short* __restrict__ Bt,
                                                    float* __restrict__ out) {
    extern __shared__ char smem[];
    unsigned short* Bl = (unsigned short*)smem;             // 2 x 32768 bf16 (128 KB)
    unsigned short* Al = (unsigned short*)(smem + 131072);  // 2 x 1024 bf16 (4 KB)
    float* ylds = (float*)smem;                             // reused post-GEMM (128.5 KB)

    const int tid  = threadIdx.x;
    const int m0   = blockIdx.x * MTILE;
    const int lane = tid & 63;
    const int w    = tid >> 6;        // wave -> cols [w*128, w*128+128)
    const int r15  = lane & 15;
    const int kq   = (lane >> 4) * 8; // k sub-offset in BK=32
    const int cl   = kq >> 3;         // logical 16B chunk 0..3

    f32x4 acc[2][8];
#pragma unroll
    for (int mi = 0; mi < 2; ++mi)
#pragma unroll
        for (int nf = 0; nf < 8; ++nf)
            acc[mi][nf] = (f32x4){0.f, 0.f, 0.f, 0.f};

    const bool aload = (tid < 128);
    const int arow = tid >> 2;
    const int akk  = (tid & 3) * 8;
    const float* xsrc = x + (size_t)(m0 + arow) * KDIM + akk;

    // prologue: tile 0
    stage_b(Bt, Bl, tid, 0);
    if (aload) {
        float4 v0 = *(const float4*)xsrc;
        float4 v1 = *(const float4*)(xsrc + 4);
        short8 o;
        o[0]=(short)f2bf(v0.x); o[1]=(short)f2bf(v0.y); o[2]=(short)f2bf(v0.z); o[3]=(short)f2bf(v0.w);
        o[4]=(short)f2bf(v1.x); o[5]=(short)f2bf(v1.y); o[6]=(short)f2bf(v1.z); o[7]=(short)f2bf(v1.w);
        *(short8*)(Al + arow * 32 + akk) = o;
    }
    __syncthreads();

    for (int t = 0; t < 32; ++t) {
        const int b = t & 1;
        float4 v0, v1;
        if (t < 31) {                          // issue next-tile loads early
            stage_b(Bt, Bl + (b ^ 1) * 32768, tid, (t + 1) * BK);
            if (aload) {
                v0 = *(const float4*)(xsrc + (t + 1) * BK);
                v1 = *(const float4*)(xsrc + (t + 1) * BK + 4);
            }
        }
        short8 af[2], bfr[8];
        const unsigned short* Ab = Al + b * 1024;
        const unsigned short* Bb = Bl + b * 32768;
#pragma unroll
        for (int mi = 0; mi < 2; ++mi)
            af[mi] = *(const short8*)(Ab + (mi * 16 + r15) * 32 + kq);
#pragma unroll
        for (int nf = 0; nf < 8; ++nf) {
            int row  = w * 128 + nf * 16 + r15;
            int phys = ((cl ^ ((row >> 1) & 3)) << 3);   // swizzled chunk
            bfr[nf] = *(const short8*)(Bb + row * 32 + phys);
        }
#pragma unroll
        for (int mi = 0; mi < 2; ++mi)
#pragma unroll
            for (int nf = 0; nf < 8; ++nf)
                acc[mi][nf] = __builtin_amdgcn_mfma_f32_16x16x32_bf16(af[mi], bfr[nf], acc[mi][nf], 0, 0, 0);
        if (t < 31 && aload) {                 // write-late: x latency hid under MFMA
            short8 o;
            o[0]=(short)f2bf(v0.x); o[1]=(short)f2bf(v0.y); o[2]=(short)f2bf(v0.z); o[3]=(short)f2bf(v0.w);
            o[4]=(short)f2bf(v1.x); o[5]=(short)f2bf(v1.y); o[6]=(short)f2bf(v1.z); o[7]=(short)f2bf(v1.w);
            *(short8*)(Al + (b ^ 1) * 1024 + arow * 32 + akk) = o;
        }
        __syncthreads();
    }

    // y (fp32) -> LDS, [32 tokens][YPAD]
    const int rr = (lane >> 4) * 4;
#pragma unroll
    for (int mi = 0; mi < 2; ++mi)
#pragma unroll
        for (int nf = 0; nf < 8; ++nf) {
            int col = w * 128 + nf * 16 + r15;
#pragma unroll
            for (int r = 0; r < 4; ++r)
                ylds[(mi * 16 + rr + r) * YPAD + col] = acc[mi][nf][r];
        }
    __syncthreads();

    // outer product + mean*sqrt(16) + rms; 16 threads/token, 8x8 tile each
    const int tok = tid >> 4;
    const int q   = tid & 15;
    const int j0  = (q >> 2) * 8;
    const int k0  = (q & 3) * 8;
    const float* yr = ylds + tok * YPAD;

    float o[8][8];
#pragma unroll
    for (int j = 0; j < 8; ++j)
#pragma unroll
        for (int k = 0; k < 8; ++k) o[j][k] = 0.f;

#pragma unroll
    for (int h = 0; h < 16; ++h) {
        float4 a0 = *(const float4*)(yr + h * 64 + j0);
        float4 a1 = *(const float4*)(yr + h * 64 + j0 + 4);
        float4 b0 = *(const float4*)(yr + h * 64 + 32 + k0);
        float4 b1 = *(const float4*)(yr + h * 64 + 32 + k0 + 4);
        float aa0[4] = {a0.x, a0.y, a0.z, a0.w};
        float aa1[4] = {a1.x, a1.y, a1.z, a1.w};
        float bb0[4] = {b0.x, b0.y, b0.z, b0.w};
        float bb1[4] = {b1.x, b1.y, b1.z, b1.w};
#pragma unroll
        for (int j = 0; j < 4; ++j)
#pragma unroll
            for (int k = 0; k < 4; ++k) {
                o[j][k]       += aa0[j] * bb0[k];
                o[j][k + 4]   += aa0[j] * bb1[k];
                o[j + 4][k]   += aa1[j] * bb0[k];
                o[j + 4][k + 4] += aa1[j] * bb1[k];
            }
    }

    float ss = 0.f;
#pragma unroll
    for (int j = 0; j < 8; ++j)
#pragma unroll
        for (int k = 0; k < 8; ++k) {
            o[j][k] *= 0.25f;                 // mean over 16 cb * sqrt(16)
            ss += o[j][k] * o[j][k];
        }
#pragma unroll
    for (int off = 1; off < 16; off <<= 1)    // reduce over the token's 16 lanes
        ss += __shfl_xor(ss, off, 64);
    const float scale = rsqrtf(ss * (1.0f / 1024.0f) + 1e-12f);

    float* orow = out + (size_t)(m0 + tok) * 1024 + k0;
#pragma unroll
    for (int j = 0; j < 8; ++j) {
        float4 w0, w1;
        w0.x = o[j][0] * scale; w0.y = o[j][1] * scale; w0.z = o[j][2] * scale; w0.w = o[j][3] * scale;
        w1.x = o[j][4] * scale; w1.y = o[j][5] * scale; w1.z = o[j][6] * scale; w1.w = o[j][7] * scale;
        *(float4*)(orow + (j0 + j) * 32)     = w0;
        *(float4*)(orow + (j0 + j) * 32 + 4) = w1;
    }
}

extern "C" void kernel_launch(void* const* d_in, const int* in_sizes, int n_in,
                              void* d_out, int out_size, void* d_ws, size_t ws_size,
                              hipStream_t stream) {
    const float* x   = (const float*)d_in[0];
    const float* wgt = (const float*)d_in[1];
    float* out = (float*)d_out;
    unsigned short* Bt = (unsigned short*)d_ws;   // 2 MB

    (void)hipFuncSetAttribute((const void*)fused_kernel,
                              hipFuncAttributeMaxDynamicSharedMemorySize, 135168);

    conv_w_kernel<<<NOUT * KDIM / 8 / 256, 256, 0, stream>>>(wgt, Bt);
    fused_kernel<<<8192 / MTILE, 512, 135168, stream>>>(x, Bt, out);
}